// Round 13
// baseline (29057.993 us; speedup 1.0000x reference)
//
#include <hip/hip_runtime.h>

// ============================================================================
// samba_hemo_to_ele: ConvT1d+GELU+BN -> 2-layer LSTM (T=6000 scan) -> MLP
// Round 13 (vs R11/R12 19.3ms): raise chain occupancy 2 -> 3 waves/SIMD.
// R12's null proved barrier drains are free; the remaining 6k cy/step over
// the 1.7k issue-bound floor is dependency-stall exposure at 2 waves/SIMD
// (ds_read ~120cy, 7-deep MFMA acc chains, serial exp->rcp gate chains).
// k_pipeline now 768 threads (12 waves, 3/SIMD):
//   chain: stride-12 tile map, wave w owns {w, w+12, w+24, w+36, (w+48)<50};
//   NT=5 -> wf[5][6]=120 VGPR; __launch_bounds__(768,3) => 170-reg budget
//   (120+20 acc+5 creg+~20 temps fits; the R9/R10 spill trap was a 128 cap).
//   SIMD tile balance 13/13/12/12. Sync wave = wave 11 (4 tiles + chores).
//   warm touch: 400 x 128B lines/slot, lanes tid<400 touch one each.
//   workers: unchanged 8-wave structure; waves 8-11 idle through barriers;
//   strided loops -> 768; C-worker o2 remapped tile = wv + 12*i < 13.
// Kept: no-nt cached rings, release/acquire coherence, per-32-step chores,
// acc<-zin after gates, [j][b] h-rings, fused-rcp gates, asm-pinned wf.
// ============================================================================

#define DEV static __device__ __forceinline__

typedef short s16x8 __attribute__((ext_vector_type(8)));
typedef float f32x4 __attribute__((ext_vector_type(4)));

// sizes
#define BB 16
#define CC 200
#define TCONV 1000
#define TT 6000
#define HH 200
#define G4 800
#define KP 224         // padded K for MFMA (7 chunks of 32)
#define XRW 232        // LDS X row pad
#define RING 256       // pre1 / z2x ring slots
#define H1R 512        // h1 ring slots
#define H2R 2048       // h2 ring slots
#define NPRE 14
#define NB1 14
#define NC 16
#define NTHR 768       // k_pipeline block size (12 waves, 3/SIMD)
#define POOLSZ 64784   // chain: 14848+12800=27648 | C: 7424+4096+53248+16=64784

DEV short f2bf(float f) {
    unsigned u = __builtin_bit_cast(unsigned, f);
    unsigned r = (u + 0x7FFFu + ((u >> 16) & 1u)) >> 16;
    return (short)r;
}
DEV unsigned ld_rlx(const unsigned* p) { return __hip_atomic_load(p, __ATOMIC_RELAXED, __HIP_MEMORY_SCOPE_AGENT); }
DEV unsigned ld_acq(const unsigned* p) { return __hip_atomic_load(p, __ATOMIC_ACQUIRE, __HIP_MEMORY_SCOPE_AGENT); }
DEV void st_rel(unsigned* p, unsigned v) { __hip_atomic_store(p, v, __ATOMIC_RELEASE, __HIP_MEMORY_SCOPE_AGENT); }
DEV f32x4 mfma16(s16x8 a, s16x8 b, f32x4 c) { return __builtin_amdgcn_mfma_f32_16x16x32_bf16(a, b, c, 0, 0, 0); }
DEV float rcpf(float x) { return __builtin_amdgcn_rcpf(x); }

// ============================ K1: ConvTranspose + GELU =====================
__global__ __launch_bounds__(256) void k_conv(const float* __restrict__ x,
                                              const float* __restrict__ w,
                                              const float* __restrict__ cb,
                                              float* __restrict__ y) {
    __shared__ float ws_[8][32][31];
    __shared__ float xs[8][38];
    const int tt = blockIdx.x, ot = blockIdx.y, b = blockIdx.z;
    const int tid = threadIdx.x;
    const int o_l = tid & 31, tq = tid >> 5;
    const int o = ot * 32 + o_l;
    const int T0base = tt * 32;
    float acc[24];
#pragma unroll
    for (int u = 0; u < 24; u++) acc[u] = 0.f;
    for (int ic = 0; ic < 200; ic += 8) {
        __syncthreads();
        for (int idx = tid; idx < 7680; idx += 256) {
            int ii = idx / 960, rem = idx % 960, oo = rem / 30, kk = rem % 30;
            int og = ot * 32 + oo;
            ws_[ii][oo][kk] = (og < 200) ? w[((size_t)(ic + ii) * 200 + og) * 30 + kk] : 0.f;
        }
        for (int idx = tid; idx < 8 * 36; idx += 256) {
            int ii = idx / 36, m = idx % 36;
            int ti = T0base - 2 + m;
            xs[ii][m] = (ti >= 0 && ti < TCONV) ? x[((size_t)b * 200 + ic + ii) * TCONV + ti] : 0.f;
        }
        __syncthreads();
#pragma unroll
        for (int ii = 0; ii < 8; ii++) {
#pragma unroll
            for (int u = 0; u < 24; u++) {
                const int T0l = tq * 4 + u / 6;
                const int r = u % 6;
                float s = 0.f;
#pragma unroll
                for (int j = 0; j < 5; j++) s += xs[ii][T0l + 4 - j] * ws_[ii][o_l][r + 6 * j];
                acc[u] += s;
            }
        }
    }
    if (o < 200) {
        const float bias = cb[o];
        const int tob = tt * 192 + tq * 24;
#pragma unroll
        for (int u = 0; u < 24; u++) {
            int t_o = tob + u;
            if (t_o < TT) {
                float v = acc[u] + bias;
                v = 0.5f * v * (1.f + erff(v * 0.70710678118654752f));
                y[((size_t)b * 200 + o) * TT + t_o] = v;
            }
        }
    }
}

// ============================ K2: BN stats =================================
__global__ __launch_bounds__(256) void k_stats(const float* __restrict__ y,
                                               const float* __restrict__ g,
                                               const float* __restrict__ be,
                                               float* __restrict__ scale,
                                               float* __restrict__ shift) {
    __shared__ float s1[256], s2[256];
    const int c = blockIdx.x, tid = threadIdx.x;
    float a1 = 0.f, a2 = 0.f;
    for (int idx = tid; idx < BB * TT; idx += 256) {
        int b = idx / TT, t = idx % TT;
        float v = y[((size_t)b * 200 + c) * TT + t];
        a1 += v;
        a2 += v * v;
    }
    s1[tid] = a1; s2[tid] = a2;
    __syncthreads();
    for (int s = 128; s > 0; s >>= 1) {
        if (tid < s) { s1[tid] += s1[tid + s]; s2[tid] += s2[tid + s]; }
        __syncthreads();
    }
    if (tid == 0) {
        float mean = s1[0] / (float)(BB * TT);
        float var = s2[0] / (float)(BB * TT) - mean * mean;
        float istd = rsqrtf(var + 1e-5f);
        float sc = g[c] * istd;
        scale[c] = sc;
        shift[c] = be[c] - mean * sc;
    }
}

// ==================== K3: BN-apply + transpose + bf16 cast =================
__global__ __launch_bounds__(256) void k_transpose(const float* __restrict__ y,
                                                   const float* __restrict__ scale,
                                                   const float* __restrict__ shift,
                                                   short* __restrict__ xhatT) {
    __shared__ float tile[32][65];
    const int tt = blockIdx.x, ct = blockIdx.y, b = blockIdx.z;
    const int tid = threadIdx.x;
    for (int idx = tid; idx < 2048; idx += 256) {
        int c_l = idx >> 6, t_l = idx & 63;
        int c = ct * 32 + c_l, t = tt * 64 + t_l;
        float v = 0.f;
        if (c < 200 && t < TT) v = y[((size_t)b * 200 + c) * TT + t] * scale[c] + shift[c];
        tile[c_l][t_l] = v;
    }
    __syncthreads();
    {
        int t_l = tid >> 2, cq = tid & 3;
        int t = tt * 64 + t_l;
        if (t < TT) {
            short tmp[8];
#pragma unroll
            for (int jj = 0; jj < 8; jj++) tmp[jj] = f2bf(tile[cq * 8 + jj][t_l]);
            *(uint4*)&xhatT[((size_t)t * 16 + b) * KP + ct * 32 + cq * 8] = *(uint4*)tmp;
        }
    }
}

// ==================== K3b: weight prep (permute n'=4j+g, bf16, pad) ========
__global__ void k_prep(const float* wi0, const float* wh0, const float* wi1, const float* wh1,
                       const float* bi0, const float* bh0, const float* bi1, const float* bh1,
                       const float* o1w, const float* o1b, const float* o2w,
                       short* Wi0p, short* Wh0p, short* Wi1p, short* Wh1p,
                       float* b1p, float* b2p, short* o1wp, float* o1bp, short* o2wp) {
    const int TOT = 716800 + 1600 + 25088 + 26624 + 112;
    int i = blockIdx.x * blockDim.x + threadIdx.x;
    int st = gridDim.x * blockDim.x;
    for (; i < TOT; i += st) {
        if (i < 716800) {
            int m = i / 179200, r = i % 179200;
            int np = r / KP, k = r % KP;
            int j = np >> 2, gg = np & 3;
            int row = gg * 200 + j;
            const float* src = (m == 0) ? wi0 : (m == 1) ? wh0 : (m == 2) ? wi1 : wh1;
            short* dst = (m == 0) ? Wi0p : (m == 1) ? Wh0p : (m == 2) ? Wi1p : Wh1p;
            dst[np * KP + k] = (k < 200) ? f2bf(src[row * 200 + k]) : (short)0;
        } else if (i < 718400) {
            int r = i - 716800;
            int which = r / 800, np = r % 800;
            int j = np >> 2, gg = np & 3;
            int row = gg * 200 + j;
            if (which == 0) b1p[np] = bi0[row] + bh0[row];
            else b2p[np] = bi1[row] + bh1[row];
        } else if (i < 743488) {
            int r = i - 718400;
            int o = r / KP, k = r % KP;
            o1wp[o * KP + k] = (o < 100 && k < 200) ? f2bf(o1w[o * 200 + k]) : (short)0;
        } else if (i < 770112) {
            int r = i - 743488;
            int p = r / 128, k = r % 128;
            o2wp[p * 128 + k] = (p < 200 && k < 100) ? f2bf(o2w[p * 100 + k]) : (short)0;
        } else {
            int o = i - 770112;
            o1bp[o] = (o < 100) ? o1b[o] : 0.f;
        }
    }
}

// ==================== K4: zero a region ====================================
__global__ void k_init(unsigned* p, int n) {
    int i = blockIdx.x * blockDim.x + threadIdx.x;
    int st = gridDim.x * blockDim.x;
    for (; i < n; i += st) p[i] = 0;
}

// ============================ pipeline =====================================
struct PipeArgs {
    const short *Wih0, *Whh0, *Wih1, *Whh1, *o1w, *o2w;
    const float *b1p, *b2p, *o1b, *o2b;
    const short* xhatT;
    const float* xmeg;
    float *pre1, *z2x;
    short *h1r, *h2r;
    unsigned* flags;  // [0:6000) pre1 | [12000:18000) z2x | 24000:A_prog 24001:B2_prog 24002:claim
    const float *h0, *c0;
    float* out;
};

// chain stage: 12 waves, stride-12 tile map (wave w: tiles w+12i, i<5).
// Swapped-operand MFMA, gates/c in registers, 1 full barrier/step.
// Wave 11 = sync wave (4 tiles + chores per 32 steps).
template <bool DO_LAG>
DEV void chain_stage(const short* __restrict__ Wp, const float* __restrict__ zring,
                     const unsigned* zflags, short* hring, int hmask,
                     unsigned* myprog, const unsigned* lagprog,
                     const float* h0p, const float* c0p, char* lds) {
    short* X0 = (short*)lds;                        // [2][16][XRW] = 14848B
    short* w6l = (short*)(lds + 2 * 16 * XRW * 2);  // [800][8] = 12800B
    const int tid = threadIdx.x;
    const int wv = tid >> 6, lane = tid & 63;
    const int col = lane & 15, quad = lane >> 4;    // col = batch b, quad = q
    const bool syncw = (wv == 11) && (lane == 0);

    for (int i = tid; i < 2 * 16 * XRW; i += NTHR) {
        int j = i % XRW;
        X0[i] = (j < 200) ? f2bf(h0p[j]) : (short)0;
    }
    for (int i = tid; i < 800 * 8; i += NTHR) {
        int n = i >> 3, kk = i & 7;
        w6l[i] = Wp[n * KP + 192 + kk];
    }
    // tile map: wave w owns tiles w + 12*i (i < 5), valid iff tile < 50
#define TILE_OF(i) (wv + 12 * (i))
    s16x8 wf[5][6];
    const s16x8 zfrag = {0, 0, 0, 0, 0, 0, 0, 0};
#pragma unroll
    for (int i = 0; i < 5; i++) {
        const int tile = TILE_OF(i);
        if (tile < 50) {
#pragma unroll
            for (int kc = 0; kc < 6; kc++)
                wf[i][kc] = *(const s16x8*)(Wp + (tile * 16 + col) * KP + kc * 32 + quad * 8);
        } else {
#pragma unroll
            for (int kc = 0; kc < 6; kc++) wf[i][kc] = zfrag;
        }
    }
#pragma unroll
    for (int i = 0; i < 5; i++)
#pragma unroll
        for (int kc = 0; kc < 6; kc++)
            asm volatile("" : "+v"(wf[i][kc]));
    float creg[5];
#pragma unroll
    for (int i = 0; i < 5; i++) {
        const int tile = TILE_OF(i);
        creg[i] = (tile < 50) ? c0p[4 * tile + quad] : 0.f;
    }
    if (syncw) {
        const volatile unsigned* zf = (const volatile unsigned*)zflags;
        for (;;) {
            unsigned ok = 1;
#pragma unroll
            for (int u = 0; u < 32; u++) ok &= zf[u];
            if (ok) break;
            __builtin_amdgcn_s_sleep(8);
        }
        (void)ld_acq(&zflags[0]);  // single inv: fresh view of slots 0..31
    }
    __syncthreads();
    f32x4 acc[5];
#pragma unroll
    for (int i = 0; i < 5; i++) {
        const int tile = TILE_OF(i);
        acc[i] = (tile < 50) ? *(const f32x4*)&zring[col * G4 + tile * 16 + quad * 4]
                             : (f32x4){0.f, 0.f, 0.f, 0.f};
    }

    for (int t = 0; t < TT; t++) {
        if ((t & 31) == 0 && syncw) {
            // (1) publish: release store (wbl2) makes h[s <= t-2] visible
            if (t >= 32) st_rel(myprog, (unsigned)(t - 1));
            // (2) verify flags [t+32, t+64): relaxed poll + one acquire
            int lo = t + 32;
            if (lo < TT) {
                int hi = lo + 32; if (hi > TT) hi = TT;
                const volatile unsigned* zf = (const volatile unsigned*)zflags;
                for (;;) {
                    unsigned ok = 1;
                    for (int u = lo; u < hi; u++) ok &= zf[u];
                    if (ok) break;
                    __builtin_amdgcn_s_sleep(8);
                }
                (void)ld_acq(&zflags[lo]);
            }
            // (3) ring-overwrite guard
            if (DO_LAG) {
                while ((int)ld_rlx(lagprog) + 184 <= t) __builtin_amdgcn_s_sleep(32);
            }
        }
        __syncthreads();  // full drain: step t-1 stores (L2-local ack) done
        const short* Xr = X0 + ((t + 1) & 1) * (16 * XRW);
        short* Xw = X0 + (t & 1) * (16 * XRW);
        // warm zin[t+1] into THIS XCD's L2: 400 x 128B lines per slot, one
        // lane each; completion covered by the MFMA+gates phase below.
        float warm = 0.f;
        const bool do_warm = (t + 1 < TT) && (tid < 400);
        if (do_warm) {
            const float* zin = zring + (size_t)((t + 1) & (RING - 1)) * (16 * G4);
            warm = *(const float*)((const char*)zin + tid * 128);
        }
        // MFMA: acc += W * h(t-1)
#pragma unroll
        for (int kc = 0; kc < 7; kc++) {
            s16x8 a = *(const s16x8*)&Xr[col * XRW + kc * 32 + quad * 8];
            if (kc < 6) {
#pragma unroll
                for (int i = 0; i < 5; i++) {
                    const int tile = TILE_OF(i);
                    if (tile < 50) acc[i] = mfma16(wf[i][kc], a, acc[i]);
                }
            } else {
#pragma unroll
                for (int i = 0; i < 5; i++) {
                    const int tile = TILE_OF(i);
                    if (tile < 50) {
                        s16x8 b6 = *(const s16x8*)&w6l[(tile * 16 + col) * 8];
                        acc[i] = mfma16(b6, a, acc[i]);
                    }
                }
            }
        }
        // gates: fused-rcp form, 5 exp + 3 rcp per element (sign-safe)
        short hb[5];
#pragma unroll
        for (int i = 0; i < 5; i++) {
            const int tile = TILE_OF(i);
            if (tile < 50) {
                const float z0 = acc[i][0], z1 = acc[i][1], z2 = acc[i][2], z3 = acc[i][3];
                float ef = __expf(-z1);
                float ei = __expf(-z0);
                float eg = __expf(-2.f * fabsf(z2));
                float itg = (1.f - eg) * rcpf((1.f + ei) * (1.f + eg));  // sigma(i)*|tanh(g)|
                float c = rcpf(1.f + ef) * creg[i] + copysignf(itg, z2);
                creg[i] = c;
                float eo = __expf(-z3);
                float ec = __expf(-2.f * fabsf(c));
                float hh = (1.f - ec) * rcpf((1.f + eo) * (1.f + ec));   // sigma(o)*|tanh(c)|
                hb[i] = f2bf(copysignf(hh, c));
            }
        }
        // keep the warm value live until here (no stall: load done long ago)
        if (do_warm) asm volatile("" :: "v"(warm));
        // acc <- zin[t+1]: an L2 HIT thanks to the warm touch
        if (t + 1 < TT) {
            const float* zin = zring + (size_t)((t + 1) & (RING - 1)) * (16 * G4);
#pragma unroll
            for (int i = 0; i < 5; i++) {
                const int tile = TILE_OF(i);
                if (tile < 50) acc[i] = *(const f32x4*)&zin[col * G4 + tile * 16 + quad * 4];
            }
        }
        // h out: X write (other dbuf) + coalesced cached store to [j][b] ring
        short* dst = hring + (size_t)(t & hmask) * (16 * KP);
#pragma unroll
        for (int i = 0; i < 5; i++) {
            const int tile = TILE_OF(i);
            if (tile < 50) {
                const int j = 4 * tile + quad;
                Xw[col * XRW + j] = hb[i];
                dst[j * 16 + col] = hb[i];
            }
        }
    }
    __syncthreads();  // full drain of final stores
    if (syncw) st_rel(myprog, (unsigned)TT);
#undef TILE_OF
}

// stage a [j=224][b=16] h-ring slot into LDS as [b=16][XRW]
DEV void stage_slot(const short* __restrict__ slot, short* __restrict__ Xl) {
    for (int idx = threadIdx.x; idx < 224 * 4; idx += NTHR) {
        int j = idx >> 2, b0 = (idx & 3) << 2;
        const uint2 v = *(const uint2*)(slot + j * 16 + b0);
        Xl[(b0 + 0) * XRW + j] = (short)(v.x & 0xffff);
        Xl[(b0 + 1) * XRW + j] = (short)(v.x >> 16);
        Xl[(b0 + 2) * XRW + j] = (short)(v.y & 0xffff);
        Xl[(b0 + 3) * XRW + j] = (short)(v.y >> 16);
    }
}

// off-chain worker GEMM: Z[16][800] = X @ Wp^T + biasp  (bf16 MFMA, [b][n] out)
// call guarded: waves 0-7 only (tile map wv + 8*i).
DEV void worker_gemm(const short* __restrict__ Wp, const float* __restrict__ biasp,
                     const short* __restrict__ xbase, int xstride,
                     const float* __restrict__ xmeg0,
                     float* __restrict__ zout) {
    const int tid = threadIdx.x;
    const int wv = tid >> 6, lane = tid & 63;
    const int col = lane & 15, quad = lane >> 4;
    s16x8 af[7];
    if (xbase) {
#pragma unroll
        for (int kc = 0; kc < 7; kc++)
            af[kc] = *(const s16x8*)&xbase[col * xstride + kc * 32 + quad * 8];
    } else {
#pragma unroll
        for (int kc = 0; kc < 7; kc++) {
            s16x8 v;
#pragma unroll
            for (int j = 0; j < 8; j++) {
                int k = kc * 32 + quad * 8 + j;
                float f = (k < 200) ? xmeg0[((size_t)col * 200 + k) * TT] : 0.f;
                v[j] = f2bf(f);
            }
            af[kc] = v;
        }
    }
#pragma unroll
    for (int i = 0; i < 7; i++) {
        int tile = wv + 8 * i;
        if (tile < 50) {
            f32x4 acc = (f32x4){0.f, 0.f, 0.f, 0.f};
#pragma unroll
            for (int kc = 0; kc < 7; kc++) {
                s16x8 b = *(const s16x8*)(Wp + (tile * 16 + col) * KP + kc * 32 + quad * 8);
                acc = mfma16(af[kc], b, acc);
            }
            int n = tile * 16 + col;
            float bs = biasp[n];
#pragma unroll
            for (int r = 0; r < 4; r++) zout[(quad * 4 + r) * G4 + n] = acc[r] + bs;
        }
    }
}

__global__ __launch_bounds__(NTHR, 3) void k_pipeline(PipeArgs P) {
    __shared__ __align__(16) char pool[POOLSZ];
    const int bid = blockIdx.x;
    const int tid = threadIdx.x;
    const int wv = tid >> 6;
    unsigned* done_pre1 = P.flags;
    unsigned* done_z2x = P.flags + 12000;
    unsigned* A_prog = P.flags + 24000;
    unsigned* B2_prog = P.flags + 24001;
    unsigned* claim = P.flags + 24002;

    if (bid == 0) {
        chain_stage<true>(P.Whh0, P.pre1, done_pre1, P.h1r, H1R - 1, A_prog, B2_prog,
                          P.h0, P.c0, pool);
    } else if (bid == 1) {
        chain_stage<false>(P.Whh1, P.z2x, done_z2x, P.h2r, H2R - 1, B2_prog, nullptr,
                           P.h0 + 200, P.c0 + 200, pool);
    } else if (bid < 2 + NPRE) {
        // pre1 worker: pre1[t] = inputs[t] @ Wih0^T + (b_ih0+b_hh0)
        int wid = bid - 2;
        for (int t = wid; t < TT; t += NPRE) {
            if (tid == 0) {
                while ((int)ld_rlx(A_prog) + RING - 8 <= t) __builtin_amdgcn_s_sleep(32);
            }
            __syncthreads();
            if (wv < 8)
                worker_gemm(P.Wih0, P.b1p,
                            (t > 0) ? (P.xhatT + (size_t)(t - 1) * (16 * KP)) : nullptr, KP,
                            P.xmeg, P.pre1 + (size_t)(t & (RING - 1)) * (16 * G4));
            __syncthreads();
            if (tid == 0) st_rel(&done_pre1[t], 1u);  // release = wbl2 + store
        }
    } else if (bid < 2 + NPRE + NB1) {
        // B1 worker: z2x[t] = h1(t) @ Wih1^T + (b_ih1+b_hh1); h1[t] visible iff A_prog > t
        int wid = bid - 2 - NPRE;
        short* Xl = (short*)pool;  // [16][XRW]
        for (int t = wid; t < TT; t += NB1) {
            if (tid == 0) {
                while ((int)ld_rlx(A_prog) <= t) __builtin_amdgcn_s_sleep(16);
                (void)ld_acq(A_prog);
                while ((int)ld_rlx(B2_prog) + RING - 8 <= t) __builtin_amdgcn_s_sleep(32);
            }
            __syncthreads();
            stage_slot(P.h1r + (size_t)(t & (H1R - 1)) * (16 * KP), Xl);
            __syncthreads();
            if (wv < 8)
                worker_gemm(P.Wih1, P.b2p, Xl, XRW, nullptr,
                            P.z2x + (size_t)(t & (RING - 1)) * (16 * G4));
            __syncthreads();
            if (tid == 0) st_rel(&done_z2x[t], 1u);
        }
    } else {
        // C worker: MLP over 64-step blocks; h2[<te] visible iff B2_prog >= te
        short* Xl = (short*)pool;                     // [16][XRW] = 7424B
        short* hid_l = (short*)(pool + 7424);         // [16][128] bf16 = 4096B
        float* outbuf = (float*)(pool + 11520);       // [4][16][208] f32 = 53248B
        volatile int* blkp = (int*)(pool + 64768);
        const int lane = tid & 63;
        const int col = lane & 15, quad = lane >> 4;
        for (int i = tid; i < 256; i += NTHR) {
            int b = i >> 4, cc = i & 15;
            hid_l[b * 128 + 112 + cc] = 0;
        }
        while (true) {
            __syncthreads();
            if (tid == 0) *blkp = (int)atomicAdd(claim, 1u);
            __syncthreads();
            int blk = *blkp;
            if (blk >= (TT + 63) / 64) break;
            int t0 = blk * 64;
            int te = min(TT, t0 + 64);
            if (tid == 0) {
                while ((int)ld_rlx(B2_prog) < te) __builtin_amdgcn_s_sleep(32);
                (void)ld_acq(B2_prog);
            }
            __syncthreads();
            for (int tb = t0; tb < te; tb += 4) {
                for (int dt = 0; dt < 4; dt++) {
                    int t = tb + dt;
                    if (t >= te) break;
                    __syncthreads();  // hid_l / Xl reuse guard
                    stage_slot(P.h2r + (size_t)(t & (H2R - 1)) * (16 * KP), Xl);
                    __syncthreads();
                    if (wv < 7) {
                        f32x4 acc = (f32x4){0.f, 0.f, 0.f, 0.f};
#pragma unroll
                        for (int kc = 0; kc < 7; kc++) {
                            s16x8 a = *(const s16x8*)&Xl[col * XRW + kc * 32 + quad * 8];
                            s16x8 b = *(const s16x8*)(P.o1w + (wv * 16 + col) * KP + kc * 32 + quad * 8);
                            acc = mfma16(a, b, acc);
                        }
                        float bs = P.o1b[wv * 16 + col];
#pragma unroll
                        for (int r = 0; r < 4; r++) {
                            float h = acc[r] + bs;
                            h = (h > 0.f) ? h : 0.f;
                            hid_l[(quad * 4 + r) * 128 + wv * 16 + col] = f2bf(h);
                        }
                    }
                    __syncthreads();
#pragma unroll
                    for (int i = 0; i < 2; i++) {
                        int tile = wv + 12 * i;  // 12 waves: wv0 covers {0,12}
                        if (tile < 13) {
                            f32x4 acc = (f32x4){0.f, 0.f, 0.f, 0.f};
#pragma unroll
                            for (int kc = 0; kc < 4; kc++) {
                                s16x8 a = *(const s16x8*)&hid_l[col * 128 + kc * 32 + quad * 8];
                                s16x8 b = *(const s16x8*)(P.o2w + (tile * 16 + col) * 128 + kc * 32 + quad * 8);
                                acc = mfma16(a, b, acc);
                            }
                            int p = tile * 16 + col;
                            if (p < 200) {
                                float bs = P.o2b[p];
#pragma unroll
                                for (int r = 0; r < 4; r++)
                                    outbuf[dt * 3328 + (quad * 4 + r) * 208 + p] = acc[r] + bs;
                            }
                        }
                    }
                }
                __syncthreads();
                int nvt = min(4, te - tb);
                for (int idx = tid; idx < 3200; idx += NTHR) {
                    int b = idx / 200, p = idx % 200;
                    float* dp = P.out + ((size_t)(b * 200 + p)) * TT + tb;
                    if (nvt == 4) {
                        float4 v = {outbuf[b * 208 + p], outbuf[3328 + b * 208 + p],
                                    outbuf[6656 + b * 208 + p], outbuf[9984 + b * 208 + p]};
                        *(float4*)dp = v;
                    } else {
                        for (int dt = 0; dt < nvt; dt++) dp[dt] = outbuf[dt * 3328 + b * 208 + p];
                    }
                }
                __syncthreads();
            }
        }
    }
}

// ============================ launcher =====================================
extern "C" void kernel_launch(void* const* d_in, const int* in_sizes, int n_in,
                              void* d_out, int out_size, void* d_ws, size_t ws_size,
                              hipStream_t stream) {
    const float* x_fmri = (const float*)d_in[0];
    const float* x_meg = (const float*)d_in[1];
    const float* conv_w = (const float*)d_in[2];
    const float* conv_b = (const float*)d_in[3];
    const float* bn_g = (const float*)d_in[4];
    const float* bn_b = (const float*)d_in[5];
    const float* w_ih0 = (const float*)d_in[6];
    const float* w_hh0 = (const float*)d_in[7];
    const float* b_ih0 = (const float*)d_in[8];
    const float* b_hh0 = (const float*)d_in[9];
    const float* w_ih1 = (const float*)d_in[10];
    const float* w_hh1 = (const float*)d_in[11];
    const float* b_ih1 = (const float*)d_in[12];
    const float* b_hh1 = (const float*)d_in[13];
    const float* out1_w = (const float*)d_in[14];
    const float* out1_b = (const float*)d_in[15];
    const float* out2_w = (const float*)d_in[16];
    const float* out2_b = (const float*)d_in[17];
    const float* h0 = (const float*)d_in[18];
    const float* c0 = (const float*)d_in[19];

    char* ws = (char*)d_ws;
    size_t off = 0;
    auto alloc = [&](size_t sz) {
        size_t o = off;
        off = (off + sz + 255) & ~(size_t)255;
        return o;
    };
    float* y = (float*)d_out;
    short* xhatT = (short*)(ws + alloc((size_t)TT * 16 * KP * 2));
    float* scale = (float*)(ws + alloc(200 * 4));
    float* shift = (float*)(ws + alloc(200 * 4));
    short* Wi0p = (short*)(ws + alloc(800 * KP * 2));
    short* Wh0p = (short*)(ws + alloc(800 * KP * 2));
    short* Wi1p = (short*)(ws + alloc(800 * KP * 2));
    short* Wh1p = (short*)(ws + alloc(800 * KP * 2));
    float* b1p = (float*)(ws + alloc(800 * 4));
    float* b2p = (float*)(ws + alloc(800 * 4));
    short* o1wp = (short*)(ws + alloc(112 * KP * 2));
    float* o1bp = (float*)(ws + alloc(112 * 4));
    short* o2wp = (short*)(ws + alloc(208 * 128 * 2));
    float* pre1 = (float*)(ws + alloc((size_t)RING * 16 * G4 * 4));
    float* z2x = (float*)(ws + alloc((size_t)RING * 16 * G4 * 4));
    short* h1r = (short*)(ws + alloc((size_t)H1R * 16 * KP * 2));
    short* h2r = (short*)(ws + alloc((size_t)H2R * 16 * KP * 2));
    unsigned* flags = (unsigned*)(ws + alloc(24016 * 4));

    k_conv<<<dim3(32, 7, 16), 256, 0, stream>>>(x_fmri, conv_w, conv_b, y);
    k_stats<<<200, 256, 0, stream>>>(y, bn_g, bn_b, scale, shift);
    k_transpose<<<dim3(94, 7, 16), 256, 0, stream>>>(y, scale, shift, xhatT);
    k_prep<<<512, 256, 0, stream>>>(w_ih0, w_hh0, w_ih1, w_hh1, b_ih0, b_hh0, b_ih1, b_hh1,
                                    out1_w, out1_b, out2_w,
                                    Wi0p, Wh0p, Wi1p, Wh1p, b1p, b2p, o1wp, o1bp, o2wp);
    {
        size_t zbytes = (size_t)((char*)(flags + 24016) - (char*)h1r);
        k_init<<<256, 256, 0, stream>>>((unsigned*)h1r, (int)(zbytes / 4));
    }

    PipeArgs P;
    P.Wih0 = Wi0p; P.Whh0 = Wh0p; P.Wih1 = Wi1p; P.Whh1 = Wh1p;
    P.o1w = o1wp; P.o2w = o2wp;
    P.b1p = b1p; P.b2p = b2p; P.o1b = o1bp; P.o2b = out2_b;
    P.xhatT = xhatT; P.xmeg = x_meg;
    P.pre1 = pre1; P.z2x = z2x; P.h1r = h1r; P.h2r = h2r;
    P.flags = flags; P.h0 = h0; P.c0 = c0;
    P.out = (float*)d_out;
    k_pipeline<<<2 + NPRE + NB1 + NC, NTHR, 0, stream>>>(P);
}

// Round 14
// 21161.833 us; speedup vs baseline: 1.3731x; 1.3731x over previous
//
#include <hip/hip_runtime.h>

// ============================================================================
// samba_hemo_to_ele: ConvT1d+GELU+BN -> 2-layer LSTM (T=6000 scan) -> MLP
// Round 14 = Round 11 (best, 19.3ms) + ONE attribute: amdgpu_waves_per_eu(2,2).
// Unified-file math exposed the session-long bug: at 2 waves/SIMD the budget
// is 256 regs/wave; every round since R5 ran at VGPR=128 (compiler occupancy
// heuristic), so wf (168 regs) could NOT be resident (128+168=296/wave x2 >
// 512/SIMD) -> Whh was re-streamed from L2 every step: 344KB / ~56B/cy/CU =
// ~6.1k cy/step = the entire unexplained gap (7.7k measured vs 1.6k issue
// model). launch_bounds(512,2) only sets MIN waves (a reg CAP, not a target);
// waves_per_eu(2,2) makes min=max=2 so the allocator actually uses ~250 regs
// and keeps the weights in registers. R13's 3-wave attempt (84 regs) made
// refetch worse -> regression, consistent.
// Everything else identical to R11: no-nt cached rings, release/acquire
// coherence, sync-wave chores per 32 steps, 1-dword L2 warm touch of zin[t+1],
// acc<-zin after gates, [j][b] h-rings + LDS re-transpose, fused-rcp gates.
// ============================================================================

#define DEV static __device__ __forceinline__

typedef short s16x8 __attribute__((ext_vector_type(8)));
typedef float f32x4 __attribute__((ext_vector_type(4)));

// sizes
#define BB 16
#define CC 200
#define TCONV 1000
#define TT 6000
#define HH 200
#define G4 800
#define KP 224         // padded K for MFMA (7 chunks of 32)
#define XRW 232        // LDS X row pad
#define RING 256       // pre1 / z2x ring slots
#define H1R 512        // h1 ring slots
#define H2R 2048       // h2 ring slots
#define NPRE 14
#define NB1 14
#define NC 16
#define POOLSZ 64784   // chain: 14848+12800=27648 | C: 7424+4096+53248+16=64784

DEV short f2bf(float f) {
    unsigned u = __builtin_bit_cast(unsigned, f);
    unsigned r = (u + 0x7FFFu + ((u >> 16) & 1u)) >> 16;
    return (short)r;
}
DEV unsigned ld_rlx(const unsigned* p) { return __hip_atomic_load(p, __ATOMIC_RELAXED, __HIP_MEMORY_SCOPE_AGENT); }
DEV unsigned ld_acq(const unsigned* p) { return __hip_atomic_load(p, __ATOMIC_ACQUIRE, __HIP_MEMORY_SCOPE_AGENT); }
DEV void st_rel(unsigned* p, unsigned v) { __hip_atomic_store(p, v, __ATOMIC_RELEASE, __HIP_MEMORY_SCOPE_AGENT); }
DEV f32x4 mfma16(s16x8 a, s16x8 b, f32x4 c) { return __builtin_amdgcn_mfma_f32_16x16x32_bf16(a, b, c, 0, 0, 0); }
DEV float rcpf(float x) { return __builtin_amdgcn_rcpf(x); }

// ============================ K1: ConvTranspose + GELU =====================
__global__ __launch_bounds__(256) void k_conv(const float* __restrict__ x,
                                              const float* __restrict__ w,
                                              const float* __restrict__ cb,
                                              float* __restrict__ y) {
    __shared__ float ws_[8][32][31];
    __shared__ float xs[8][38];
    const int tt = blockIdx.x, ot = blockIdx.y, b = blockIdx.z;
    const int tid = threadIdx.x;
    const int o_l = tid & 31, tq = tid >> 5;
    const int o = ot * 32 + o_l;
    const int T0base = tt * 32;
    float acc[24];
#pragma unroll
    for (int u = 0; u < 24; u++) acc[u] = 0.f;
    for (int ic = 0; ic < 200; ic += 8) {
        __syncthreads();
        for (int idx = tid; idx < 7680; idx += 256) {
            int ii = idx / 960, rem = idx % 960, oo = rem / 30, kk = rem % 30;
            int og = ot * 32 + oo;
            ws_[ii][oo][kk] = (og < 200) ? w[((size_t)(ic + ii) * 200 + og) * 30 + kk] : 0.f;
        }
        for (int idx = tid; idx < 8 * 36; idx += 256) {
            int ii = idx / 36, m = idx % 36;
            int ti = T0base - 2 + m;
            xs[ii][m] = (ti >= 0 && ti < TCONV) ? x[((size_t)b * 200 + ic + ii) * TCONV + ti] : 0.f;
        }
        __syncthreads();
#pragma unroll
        for (int ii = 0; ii < 8; ii++) {
#pragma unroll
            for (int u = 0; u < 24; u++) {
                const int T0l = tq * 4 + u / 6;
                const int r = u % 6;
                float s = 0.f;
#pragma unroll
                for (int j = 0; j < 5; j++) s += xs[ii][T0l + 4 - j] * ws_[ii][o_l][r + 6 * j];
                acc[u] += s;
            }
        }
    }
    if (o < 200) {
        const float bias = cb[o];
        const int tob = tt * 192 + tq * 24;
#pragma unroll
        for (int u = 0; u < 24; u++) {
            int t_o = tob + u;
            if (t_o < TT) {
                float v = acc[u] + bias;
                v = 0.5f * v * (1.f + erff(v * 0.70710678118654752f));
                y[((size_t)b * 200 + o) * TT + t_o] = v;
            }
        }
    }
}

// ============================ K2: BN stats =================================
__global__ __launch_bounds__(256) void k_stats(const float* __restrict__ y,
                                               const float* __restrict__ g,
                                               const float* __restrict__ be,
                                               float* __restrict__ scale,
                                               float* __restrict__ shift) {
    __shared__ float s1[256], s2[256];
    const int c = blockIdx.x, tid = threadIdx.x;
    float a1 = 0.f, a2 = 0.f;
    for (int idx = tid; idx < BB * TT; idx += 256) {
        int b = idx / TT, t = idx % TT;
        float v = y[((size_t)b * 200 + c) * TT + t];
        a1 += v;
        a2 += v * v;
    }
    s1[tid] = a1; s2[tid] = a2;
    __syncthreads();
    for (int s = 128; s > 0; s >>= 1) {
        if (tid < s) { s1[tid] += s1[tid + s]; s2[tid] += s2[tid + s]; }
        __syncthreads();
    }
    if (tid == 0) {
        float mean = s1[0] / (float)(BB * TT);
        float var = s2[0] / (float)(BB * TT) - mean * mean;
        float istd = rsqrtf(var + 1e-5f);
        float sc = g[c] * istd;
        scale[c] = sc;
        shift[c] = be[c] - mean * sc;
    }
}

// ==================== K3: BN-apply + transpose + bf16 cast =================
__global__ __launch_bounds__(256) void k_transpose(const float* __restrict__ y,
                                                   const float* __restrict__ scale,
                                                   const float* __restrict__ shift,
                                                   short* __restrict__ xhatT) {
    __shared__ float tile[32][65];
    const int tt = blockIdx.x, ct = blockIdx.y, b = blockIdx.z;
    const int tid = threadIdx.x;
    for (int idx = tid; idx < 2048; idx += 256) {
        int c_l = idx >> 6, t_l = idx & 63;
        int c = ct * 32 + c_l, t = tt * 64 + t_l;
        float v = 0.f;
        if (c < 200 && t < TT) v = y[((size_t)b * 200 + c) * TT + t] * scale[c] + shift[c];
        tile[c_l][t_l] = v;
    }
    __syncthreads();
    {
        int t_l = tid >> 2, cq = tid & 3;
        int t = tt * 64 + t_l;
        if (t < TT) {
            short tmp[8];
#pragma unroll
            for (int jj = 0; jj < 8; jj++) tmp[jj] = f2bf(tile[cq * 8 + jj][t_l]);
            *(uint4*)&xhatT[((size_t)t * 16 + b) * KP + ct * 32 + cq * 8] = *(uint4*)tmp;
        }
    }
}

// ==================== K3b: weight prep (permute n'=4j+g, bf16, pad) ========
__global__ void k_prep(const float* wi0, const float* wh0, const float* wi1, const float* wh1,
                       const float* bi0, const float* bh0, const float* bi1, const float* bh1,
                       const float* o1w, const float* o1b, const float* o2w,
                       short* Wi0p, short* Wh0p, short* Wi1p, short* Wh1p,
                       float* b1p, float* b2p, short* o1wp, float* o1bp, short* o2wp) {
    const int TOT = 716800 + 1600 + 25088 + 26624 + 112;
    int i = blockIdx.x * blockDim.x + threadIdx.x;
    int st = gridDim.x * blockDim.x;
    for (; i < TOT; i += st) {
        if (i < 716800) {
            int m = i / 179200, r = i % 179200;
            int np = r / KP, k = r % KP;
            int j = np >> 2, gg = np & 3;
            int row = gg * 200 + j;
            const float* src = (m == 0) ? wi0 : (m == 1) ? wh0 : (m == 2) ? wi1 : wh1;
            short* dst = (m == 0) ? Wi0p : (m == 1) ? Wh0p : (m == 2) ? Wi1p : Wh1p;
            dst[np * KP + k] = (k < 200) ? f2bf(src[row * 200 + k]) : (short)0;
        } else if (i < 718400) {
            int r = i - 716800;
            int which = r / 800, np = r % 800;
            int j = np >> 2, gg = np & 3;
            int row = gg * 200 + j;
            if (which == 0) b1p[np] = bi0[row] + bh0[row];
            else b2p[np] = bi1[row] + bh1[row];
        } else if (i < 743488) {
            int r = i - 718400;
            int o = r / KP, k = r % KP;
            o1wp[o * KP + k] = (o < 100 && k < 200) ? f2bf(o1w[o * 200 + k]) : (short)0;
        } else if (i < 770112) {
            int r = i - 743488;
            int p = r / 128, k = r % 128;
            o2wp[p * 128 + k] = (p < 200 && k < 100) ? f2bf(o2w[p * 100 + k]) : (short)0;
        } else {
            int o = i - 770112;
            o1bp[o] = (o < 100) ? o1b[o] : 0.f;
        }
    }
}

// ==================== K4: zero a region ====================================
__global__ void k_init(unsigned* p, int n) {
    int i = blockIdx.x * blockDim.x + threadIdx.x;
    int st = gridDim.x * blockDim.x;
    for (; i < n; i += st) p[i] = 0;
}

// ============================ pipeline =====================================
struct PipeArgs {
    const short *Wih0, *Whh0, *Wih1, *Whh1, *o1w, *o2w;
    const float *b1p, *b2p, *o1b, *o2b;
    const short* xhatT;
    const float* xmeg;
    float *pre1, *z2x;
    short *h1r, *h2r;
    unsigned* flags;  // [0:6000) pre1 | [12000:18000) z2x | 24000:A_prog 24001:B2_prog 24002:claim
    const float *h0, *c0;
    float* out;
};

// chain stage: swapped-operand MFMA, gates/c in registers, 1 full barrier/step.
// Wave 7 = sync wave: tile 49 + group chores per 32 steps.
// Per step: [boundary chores] -> barrier -> warm-touch zin[t+1] (1 dword/lane,
// covers this wave's 4 cache lines; completes under MFMA+gates) -> MFMA ->
// gates -> asm-use warm -> acc <- zin[t+1] (L2 HIT) -> h out (cached stores).
template <bool DO_LAG>
DEV void chain_stage(const short* __restrict__ Wp, const float* __restrict__ zring,
                     const unsigned* zflags, short* hring, int hmask,
                     unsigned* myprog, const unsigned* lagprog,
                     const float* h0p, const float* c0p, char* lds) {
    short* X0 = (short*)lds;                        // [2][16][XRW] = 14848B
    short* w6l = (short*)(lds + 2 * 16 * XRW * 2);  // [800][8] = 12800B
    const int tid = threadIdx.x;
    const int wv = tid >> 6, lane = tid & 63;
    const int col = lane & 15, quad = lane >> 4;    // col = batch b, quad = q
    const bool syncw = (wv == 7) && (lane == 0);

    for (int i = tid; i < 2 * 16 * XRW; i += 512) {
        int j = i % XRW;
        X0[i] = (j < 200) ? f2bf(h0p[j]) : (short)0;
    }
    for (int i = tid; i < 800 * 8; i += 512) {
        int n = i >> 3, kk = i & 7;
        w6l[i] = Wp[n * KP + 192 + kk];
    }
    // tile map: wv<7 -> wv*7+i (i<7) = tiles 0..48 ; wv7 -> tile 49 (i==0)
#define TILE_OF(i) ((wv < 7) ? (wv * 7 + (i)) : (((i) == 0) ? 49 : 50))
    s16x8 wf[7][6];
    const s16x8 zfrag = {0, 0, 0, 0, 0, 0, 0, 0};
#pragma unroll
    for (int i = 0; i < 7; i++) {
        const int tile = TILE_OF(i);
        if (tile < 50) {
#pragma unroll
            for (int kc = 0; kc < 6; kc++)
                wf[i][kc] = *(const s16x8*)(Wp + (tile * 16 + col) * KP + kc * 32 + quad * 8);
        } else {
#pragma unroll
            for (int kc = 0; kc < 6; kc++) wf[i][kc] = zfrag;
        }
    }
#pragma unroll
    for (int i = 0; i < 7; i++)
#pragma unroll
        for (int kc = 0; kc < 6; kc++)
            asm volatile("" : "+v"(wf[i][kc]));
    float creg[7];
#pragma unroll
    for (int i = 0; i < 7; i++) {
        const int tile = TILE_OF(i);
        creg[i] = (tile < 50) ? c0p[4 * tile + quad] : 0.f;
    }
    if (syncw) {
        const volatile unsigned* zf = (const volatile unsigned*)zflags;
        for (;;) {
            unsigned ok = 1;
#pragma unroll
            for (int u = 0; u < 32; u++) ok &= zf[u];
            if (ok) break;
            __builtin_amdgcn_s_sleep(8);
        }
        (void)ld_acq(&zflags[0]);  // single inv: fresh view of slots 0..31
    }
    __syncthreads();
    f32x4 acc[7];
#pragma unroll
    for (int i = 0; i < 7; i++) {
        const int tile = TILE_OF(i);
        acc[i] = (tile < 50) ? *(const f32x4*)&zring[col * G4 + tile * 16 + quad * 4]
                             : (f32x4){0.f, 0.f, 0.f, 0.f};
    }
    // warm-touch address: this wave's tiles are contiguous (448B per b-row);
    // lane -> (row = lane&15, lineidx = lane>>4): 4 x 128B touches cover it.
    const int warm_off = (lane & 15) * (G4 * 4) + wv * 448 + (lane >> 4) * 128;

    for (int t = 0; t < TT; t++) {
        if ((t & 31) == 0 && syncw) {
            // (1) publish: release store (wbl2) makes h[s <= t-2] visible
            if (t >= 32) st_rel(myprog, (unsigned)(t - 1));
            // (2) verify flags [t+32, t+64): relaxed poll + one acquire
            int lo = t + 32;
            if (lo < TT) {
                int hi = lo + 32; if (hi > TT) hi = TT;
                const volatile unsigned* zf = (const volatile unsigned*)zflags;
                for (;;) {
                    unsigned ok = 1;
                    for (int u = lo; u < hi; u++) ok &= zf[u];
                    if (ok) break;
                    __builtin_amdgcn_s_sleep(8);
                }
                (void)ld_acq(&zflags[lo]);
            }
            // (3) ring-overwrite guard
            if (DO_LAG) {
                while ((int)ld_rlx(lagprog) + 184 <= t) __builtin_amdgcn_s_sleep(32);
            }
        }
        __syncthreads();  // full drain: step t-1 stores (L2-local ack) done
        const short* Xr = X0 + ((t + 1) & 1) * (16 * XRW);
        short* Xw = X0 + (t & 1) * (16 * XRW);
        // warm zin[t+1] into THIS XCD's L2 (1 dword/lane); completion is
        // covered by the MFMA+gates phase below.
        float warm = 0.f;
        const bool do_warm = (t + 1 < TT) && (wv < 7);
        if (do_warm) {
            const float* zin = zring + (size_t)((t + 1) & (RING - 1)) * (16 * G4);
            warm = *(const float*)((const char*)zin + warm_off);
        }
        // MFMA: acc += W * h(t-1)
#pragma unroll
        for (int kc = 0; kc < 7; kc++) {
            s16x8 a = *(const s16x8*)&Xr[col * XRW + kc * 32 + quad * 8];
            if (kc < 6) {
#pragma unroll
                for (int i = 0; i < 7; i++) {
                    const int tile = TILE_OF(i);
                    if (tile < 50) acc[i] = mfma16(wf[i][kc], a, acc[i]);
                }
            } else {
#pragma unroll
                for (int i = 0; i < 7; i++) {
                    const int tile = TILE_OF(i);
                    if (tile < 50) {
                        s16x8 b6 = *(const s16x8*)&w6l[(tile * 16 + col) * 8];
                        acc[i] = mfma16(b6, a, acc[i]);
                    }
                }
            }
        }
        // gates: fused-rcp form, 5 exp + 3 rcp per element (sign-safe)
        short hb[7];
#pragma unroll
        for (int i = 0; i < 7; i++) {
            const int tile = TILE_OF(i);
            if (tile < 50) {
                const float z0 = acc[i][0], z1 = acc[i][1], z2 = acc[i][2], z3 = acc[i][3];
                float ef = __expf(-z1);
                float ei = __expf(-z0);
                float eg = __expf(-2.f * fabsf(z2));
                float itg = (1.f - eg) * rcpf((1.f + ei) * (1.f + eg));  // sigma(i)*|tanh(g)|
                float c = rcpf(1.f + ef) * creg[i] + copysignf(itg, z2);
                creg[i] = c;
                float eo = __expf(-z3);
                float ec = __expf(-2.f * fabsf(c));
                float hh = (1.f - ec) * rcpf((1.f + eo) * (1.f + ec));   // sigma(o)*|tanh(c)|
                hb[i] = f2bf(copysignf(hh, c));
            }
        }
        // keep the warm value live until here (no stall: load done long ago)
        if (do_warm) asm volatile("" :: "v"(warm));
        // acc <- zin[t+1]: an L2 HIT thanks to the warm touch
        if (t + 1 < TT) {
            const float* zin = zring + (size_t)((t + 1) & (RING - 1)) * (16 * G4);
#pragma unroll
            for (int i = 0; i < 7; i++) {
                const int tile = TILE_OF(i);
                if (tile < 50) acc[i] = *(const f32x4*)&zin[col * G4 + tile * 16 + quad * 4];
            }
        }
        // h out: X write (other dbuf) + coalesced cached store to [j][b] ring
        short* dst = hring + (size_t)(t & hmask) * (16 * KP);
#pragma unroll
        for (int i = 0; i < 7; i++) {
            const int tile = TILE_OF(i);
            if (tile < 50) {
                const int j = 4 * tile + quad;
                Xw[col * XRW + j] = hb[i];
                dst[j * 16 + col] = hb[i];
            }
        }
    }
    __syncthreads();  // full drain of final stores
    if (syncw) st_rel(myprog, (unsigned)TT);
#undef TILE_OF
}

// stage a [j=224][b=16] h-ring slot into LDS as [b=16][XRW]
DEV void stage_slot(const short* __restrict__ slot, short* __restrict__ Xl) {
    for (int idx = threadIdx.x; idx < 224 * 4; idx += 512) {
        int j = idx >> 2, b0 = (idx & 3) << 2;
        const uint2 v = *(const uint2*)(slot + j * 16 + b0);
        Xl[(b0 + 0) * XRW + j] = (short)(v.x & 0xffff);
        Xl[(b0 + 1) * XRW + j] = (short)(v.x >> 16);
        Xl[(b0 + 2) * XRW + j] = (short)(v.y & 0xffff);
        Xl[(b0 + 3) * XRW + j] = (short)(v.y >> 16);
    }
}

// off-chain worker GEMM: Z[16][800] = X @ Wp^T + biasp  (bf16 MFMA, [b][n] out)
DEV void worker_gemm(const short* __restrict__ Wp, const float* __restrict__ biasp,
                     const short* __restrict__ xbase, int xstride,
                     const float* __restrict__ xmeg0,
                     float* __restrict__ zout) {
    const int tid = threadIdx.x;
    const int wv = tid >> 6, lane = tid & 63;
    const int col = lane & 15, quad = lane >> 4;
    s16x8 af[7];
    if (xbase) {
#pragma unroll
        for (int kc = 0; kc < 7; kc++)
            af[kc] = *(const s16x8*)&xbase[col * xstride + kc * 32 + quad * 8];
    } else {
#pragma unroll
        for (int kc = 0; kc < 7; kc++) {
            s16x8 v;
#pragma unroll
            for (int j = 0; j < 8; j++) {
                int k = kc * 32 + quad * 8 + j;
                float f = (k < 200) ? xmeg0[((size_t)col * 200 + k) * TT] : 0.f;
                v[j] = f2bf(f);
            }
            af[kc] = v;
        }
    }
#pragma unroll
    for (int i = 0; i < 7; i++) {
        int tile = wv + 8 * i;
        if (tile < 50) {
            f32x4 acc = (f32x4){0.f, 0.f, 0.f, 0.f};
#pragma unroll
            for (int kc = 0; kc < 7; kc++) {
                s16x8 b = *(const s16x8*)(Wp + (tile * 16 + col) * KP + kc * 32 + quad * 8);
                acc = mfma16(af[kc], b, acc);
            }
            int n = tile * 16 + col;
            float bs = biasp[n];
#pragma unroll
            for (int r = 0; r < 4; r++) zout[(quad * 4 + r) * G4 + n] = acc[r] + bs;
        }
    }
}

__global__ __launch_bounds__(512)
__attribute__((amdgpu_waves_per_eu(2, 2)))
void k_pipeline(PipeArgs P) {
    __shared__ __align__(16) char pool[POOLSZ];
    const int bid = blockIdx.x;
    const int tid = threadIdx.x;
    unsigned* done_pre1 = P.flags;
    unsigned* done_z2x = P.flags + 12000;
    unsigned* A_prog = P.flags + 24000;
    unsigned* B2_prog = P.flags + 24001;
    unsigned* claim = P.flags + 24002;

    if (bid == 0) {
        chain_stage<true>(P.Whh0, P.pre1, done_pre1, P.h1r, H1R - 1, A_prog, B2_prog,
                          P.h0, P.c0, pool);
    } else if (bid == 1) {
        chain_stage<false>(P.Whh1, P.z2x, done_z2x, P.h2r, H2R - 1, B2_prog, nullptr,
                           P.h0 + 200, P.c0 + 200, pool);
    } else if (bid < 2 + NPRE) {
        // pre1 worker: pre1[t] = inputs[t] @ Wih0^T + (b_ih0+b_hh0)
        int wid = bid - 2;
        for (int t = wid; t < TT; t += NPRE) {
            if (tid == 0) {
                while ((int)ld_rlx(A_prog) + RING - 8 <= t) __builtin_amdgcn_s_sleep(32);
            }
            __syncthreads();
            worker_gemm(P.Wih0, P.b1p,
                        (t > 0) ? (P.xhatT + (size_t)(t - 1) * (16 * KP)) : nullptr, KP,
                        P.xmeg, P.pre1 + (size_t)(t & (RING - 1)) * (16 * G4));
            __syncthreads();
            if (tid == 0) st_rel(&done_pre1[t], 1u);  // release = wbl2 + store
        }
    } else if (bid < 2 + NPRE + NB1) {
        // B1 worker: z2x[t] = h1(t) @ Wih1^T + (b_ih1+b_hh1); h1[t] visible iff A_prog > t
        int wid = bid - 2 - NPRE;
        short* Xl = (short*)pool;  // [16][XRW]
        for (int t = wid; t < TT; t += NB1) {
            if (tid == 0) {
                while ((int)ld_rlx(A_prog) <= t) __builtin_amdgcn_s_sleep(16);
                (void)ld_acq(A_prog);
                while ((int)ld_rlx(B2_prog) + RING - 8 <= t) __builtin_amdgcn_s_sleep(32);
            }
            __syncthreads();
            stage_slot(P.h1r + (size_t)(t & (H1R - 1)) * (16 * KP), Xl);
            __syncthreads();
            worker_gemm(P.Wih1, P.b2p, Xl, XRW, nullptr,
                        P.z2x + (size_t)(t & (RING - 1)) * (16 * G4));
            __syncthreads();
            if (tid == 0) st_rel(&done_z2x[t], 1u);
        }
    } else {
        // C worker: MLP over 64-step blocks; h2[<te] visible iff B2_prog >= te
        short* Xl = (short*)pool;                     // [16][XRW] = 7424B
        short* hid_l = (short*)(pool + 7424);         // [16][128] bf16 = 4096B
        float* outbuf = (float*)(pool + 11520);       // [4][16][208] f32 = 53248B
        volatile int* blkp = (int*)(pool + 64768);
        const int wv = tid >> 6, lane = tid & 63;
        const int col = lane & 15, quad = lane >> 4;
        for (int i = tid; i < 256; i += 512) {
            int b = i >> 4, cc = i & 15;
            hid_l[b * 128 + 112 + cc] = 0;
        }
        while (true) {
            __syncthreads();
            if (tid == 0) *blkp = (int)atomicAdd(claim, 1u);
            __syncthreads();
            int blk = *blkp;
            if (blk >= (TT + 63) / 64) break;
            int t0 = blk * 64;
            int te = min(TT, t0 + 64);
            if (tid == 0) {
                while ((int)ld_rlx(B2_prog) < te) __builtin_amdgcn_s_sleep(32);
                (void)ld_acq(B2_prog);
            }
            __syncthreads();
            for (int tb = t0; tb < te; tb += 4) {
                for (int dt = 0; dt < 4; dt++) {
                    int t = tb + dt;
                    if (t >= te) break;
                    __syncthreads();  // hid_l / Xl reuse guard
                    stage_slot(P.h2r + (size_t)(t & (H2R - 1)) * (16 * KP), Xl);
                    __syncthreads();
                    if (wv < 7) {
                        f32x4 acc = (f32x4){0.f, 0.f, 0.f, 0.f};
#pragma unroll
                        for (int kc = 0; kc < 7; kc++) {
                            s16x8 a = *(const s16x8*)&Xl[col * XRW + kc * 32 + quad * 8];
                            s16x8 b = *(const s16x8*)(P.o1w + (wv * 16 + col) * KP + kc * 32 + quad * 8);
                            acc = mfma16(a, b, acc);
                        }
                        float bs = P.o1b[wv * 16 + col];
#pragma unroll
                        for (int r = 0; r < 4; r++) {
                            float h = acc[r] + bs;
                            h = (h > 0.f) ? h : 0.f;
                            hid_l[(quad * 4 + r) * 128 + wv * 16 + col] = f2bf(h);
                        }
                    }
                    __syncthreads();
#pragma unroll
                    for (int i = 0; i < 2; i++) {
                        int tile = wv + 8 * i;
                        if (tile < 13) {
                            f32x4 acc = (f32x4){0.f, 0.f, 0.f, 0.f};
#pragma unroll
                            for (int kc = 0; kc < 4; kc++) {
                                s16x8 a = *(const s16x8*)&hid_l[col * 128 + kc * 32 + quad * 8];
                                s16x8 b = *(const s16x8*)(P.o2w + (tile * 16 + col) * 128 + kc * 32 + quad * 8);
                                acc = mfma16(a, b, acc);
                            }
                            int p = tile * 16 + col;
                            if (p < 200) {
                                float bs = P.o2b[p];
#pragma unroll
                                for (int r = 0; r < 4; r++)
                                    outbuf[dt * 3328 + (quad * 4 + r) * 208 + p] = acc[r] + bs;
                            }
                        }
                    }
                }
                __syncthreads();
                int nvt = min(4, te - tb);
                for (int idx = tid; idx < 3200; idx += 512) {
                    int b = idx / 200, p = idx % 200;
                    float* dp = P.out + ((size_t)(b * 200 + p)) * TT + tb;
                    if (nvt == 4) {
                        float4 v = {outbuf[b * 208 + p], outbuf[3328 + b * 208 + p],
                                    outbuf[6656 + b * 208 + p], outbuf[9984 + b * 208 + p]};
                        *(float4*)dp = v;
                    } else {
                        for (int dt = 0; dt < nvt; dt++) dp[dt] = outbuf[dt * 3328 + b * 208 + p];
                    }
                }
                __syncthreads();
            }
        }
    }
}

// ============================ launcher =====================================
extern "C" void kernel_launch(void* const* d_in, const int* in_sizes, int n_in,
                              void* d_out, int out_size, void* d_ws, size_t ws_size,
                              hipStream_t stream) {
    const float* x_fmri = (const float*)d_in[0];
    const float* x_meg = (const float*)d_in[1];
    const float* conv_w = (const float*)d_in[2];
    const float* conv_b = (const float*)d_in[3];
    const float* bn_g = (const float*)d_in[4];
    const float* bn_b = (const float*)d_in[5];
    const float* w_ih0 = (const float*)d_in[6];
    const float* w_hh0 = (const float*)d_in[7];
    const float* b_ih0 = (const float*)d_in[8];
    const float* b_hh0 = (const float*)d_in[9];
    const float* w_ih1 = (const float*)d_in[10];
    const float* w_hh1 = (const float*)d_in[11];
    const float* b_ih1 = (const float*)d_in[12];
    const float* b_hh1 = (const float*)d_in[13];
    const float* out1_w = (const float*)d_in[14];
    const float* out1_b = (const float*)d_in[15];
    const float* out2_w = (const float*)d_in[16];
    const float* out2_b = (const float*)d_in[17];
    const float* h0 = (const float*)d_in[18];
    const float* c0 = (const float*)d_in[19];

    char* ws = (char*)d_ws;
    size_t off = 0;
    auto alloc = [&](size_t sz) {
        size_t o = off;
        off = (off + sz + 255) & ~(size_t)255;
        return o;
    };
    float* y = (float*)d_out;
    short* xhatT = (short*)(ws + alloc((size_t)TT * 16 * KP * 2));
    float* scale = (float*)(ws + alloc(200 * 4));
    float* shift = (float*)(ws + alloc(200 * 4));
    short* Wi0p = (short*)(ws + alloc(800 * KP * 2));
    short* Wh0p = (short*)(ws + alloc(800 * KP * 2));
    short* Wi1p = (short*)(ws + alloc(800 * KP * 2));
    short* Wh1p = (short*)(ws + alloc(800 * KP * 2));
    float* b1p = (float*)(ws + alloc(800 * 4));
    float* b2p = (float*)(ws + alloc(800 * 4));
    short* o1wp = (short*)(ws + alloc(112 * KP * 2));
    float* o1bp = (float*)(ws + alloc(112 * 4));
    short* o2wp = (short*)(ws + alloc(208 * 128 * 2));
    float* pre1 = (float*)(ws + alloc((size_t)RING * 16 * G4 * 4));
    float* z2x = (float*)(ws + alloc((size_t)RING * 16 * G4 * 4));
    short* h1r = (short*)(ws + alloc((size_t)H1R * 16 * KP * 2));
    short* h2r = (short*)(ws + alloc((size_t)H2R * 16 * KP * 2));
    unsigned* flags = (unsigned*)(ws + alloc(24016 * 4));

    k_conv<<<dim3(32, 7, 16), 256, 0, stream>>>(x_fmri, conv_w, conv_b, y);
    k_stats<<<200, 256, 0, stream>>>(y, bn_g, bn_b, scale, shift);
    k_transpose<<<dim3(94, 7, 16), 256, 0, stream>>>(y, scale, shift, xhatT);
    k_prep<<<512, 256, 0, stream>>>(w_ih0, w_hh0, w_ih1, w_hh1, b_ih0, b_hh0, b_ih1, b_hh1,
                                    out1_w, out1_b, out2_w,
                                    Wi0p, Wh0p, Wi1p, Wh1p, b1p, b2p, o1wp, o1bp, o2wp);
    {
        size_t zbytes = (size_t)((char*)(flags + 24016) - (char*)h1r);
        k_init<<<256, 256, 0, stream>>>((unsigned*)h1r, (int)(zbytes / 4));
    }

    PipeArgs P;
    P.Wih0 = Wi0p; P.Whh0 = Wh0p; P.Wih1 = Wi1p; P.Whh1 = Wh1p;
    P.o1w = o1wp; P.o2w = o2wp;
    P.b1p = b1p; P.b2p = b2p; P.o1b = o1bp; P.o2b = out2_b;
    P.xhatT = xhatT; P.xmeg = x_meg;
    P.pre1 = pre1; P.z2x = z2x; P.h1r = h1r; P.h2r = h2r;
    P.flags = flags; P.h0 = h0; P.c0 = c0;
    P.out = (float*)d_out;
    k_pipeline<<<2 + NPRE + NB1 + NC, 512, 0, stream>>>(P);
}